// Round 1
// baseline (451.282 us; speedup 1.0000x reference)
//
#include <hip/hip_runtime.h>
#include <hip/hip_bf16.h>

typedef __bf16 bf16_t;
typedef bf16_t bf16x8 __attribute__((ext_vector_type(8)));
typedef float floatx4 __attribute__((ext_vector_type(4)));

#define GN 4096
#define GK 1024
#define BM 128
#define BN 128
#define BK 32
#define LDK 40  // padded LDS row stride (bf16 elems): 80 B rows -> 2-way (free) bank pattern

// fp32 -> bf16 RNE via bit ops (inputs are finite random normals; no NaN handling needed)
static __device__ __forceinline__ unsigned short f2bf(float f) {
    unsigned u = __builtin_bit_cast(unsigned, f);
    u += 0x7fffu + ((u >> 16) & 1u);
    return (unsigned short)(u >> 16);
}

// Per-row: bf16 cast + inverse L2 norm
__global__ __launch_bounds__(256)
void prep_kernel(const float* __restrict__ X, unsigned short* __restrict__ Xb,
                 float* __restrict__ inv_norm) {
    const int i = blockIdx.x;
    const int tid = threadIdx.x;
    const float* row = X + (size_t)i * GK;
    unsigned short* rowb = Xb + (size_t)i * GK;
    float ss = 0.f;
    #pragma unroll
    for (int j = tid; j < GK; j += 256) {
        float f = row[j];
        ss += f * f;
        rowb[j] = f2bf(f);
    }
    #pragma unroll
    for (int off = 32; off > 0; off >>= 1) ss += __shfl_down(ss, off);
    __shared__ float sw[4];
    int wave = tid >> 6, lane = tid & 63;
    if (lane == 0) sw[wave] = ss;
    __syncthreads();
    if (tid == 0) inv_norm[i] = 1.0f / sqrtf(sw[0] + sw[1] + sw[2] + sw[3]);
}

// C[M,N] = A[M,K] * B[N,K]^T, bf16 in (raw bits), fp32 out.
// 128x128 block tile, 4 waves each computing a 64x64 quadrant via 4x4 grid of 16x16x32 MFMAs.
__global__ __launch_bounds__(256)
void gemm_bt(const unsigned short* __restrict__ A, const unsigned short* __restrict__ B,
             float* __restrict__ C) {
    __shared__ __align__(16) unsigned short As[BM * LDK];
    __shared__ __align__(16) unsigned short Bs[BN * LDK];

    const int tid = threadIdx.x;
    const int wave = tid >> 6, lane = tid & 63;
    const int bm = blockIdx.y * BM, bn = blockIdx.x * BN;
    const int wm = (wave >> 1) * 64, wn = (wave & 1) * 64;
    const int lrow = lane & 15;   // row/col within 16-tile
    const int kq = lane >> 4;     // k-quad: k offset = kq*8

    floatx4 acc[4][4] = {};

    for (int k0 = 0; k0 < GK; k0 += BK) {
        // Stage 128x32 A and B tiles: 512 chunks of 16 B each, 2 chunks/thread.
        #pragma unroll
        for (int s = 0; s < 2; ++s) {
            int q = tid + s * 256;
            int r = q >> 2, c = q & 3;      // row in tile, 8-elem column chunk
            const int4 av = *(const int4*)(A + (size_t)(bm + r) * GK + k0 + c * 8);
            const int4 bv = *(const int4*)(B + (size_t)(bn + r) * GK + k0 + c * 8);
            *(int4*)(As + r * LDK + c * 8) = av;
            *(int4*)(Bs + r * LDK + c * 8) = bv;
        }
        __syncthreads();

        bf16x8 af[4], bfr[4];
        #pragma unroll
        for (int t = 0; t < 4; ++t)
            af[t] = *(const bf16x8*)(As + (wm + t * 16 + lrow) * LDK + kq * 8);
        #pragma unroll
        for (int u = 0; u < 4; ++u)
            bfr[u] = *(const bf16x8*)(Bs + (wn + u * 16 + lrow) * LDK + kq * 8);
        #pragma unroll
        for (int t = 0; t < 4; ++t)
            #pragma unroll
            for (int u = 0; u < 4; ++u)
                acc[t][u] = __builtin_amdgcn_mfma_f32_16x16x32_bf16(af[t], bfr[u], acc[t][u], 0, 0, 0);
        __syncthreads();
    }

    // Epilogue: C/D layout col=lane&15, row=(lane>>4)*4+reg
    const int cn = lane & 15;
    const int rq = lane >> 4;
    #pragma unroll
    for (int t = 0; t < 4; ++t)
        #pragma unroll
        for (int u = 0; u < 4; ++u)
            #pragma unroll
            for (int r = 0; r < 4; ++r) {
                int row = bm + wm + t * 16 + rq * 4 + r;
                int col = bn + wn + u * 16 + cn;
                C[(size_t)row * GN + col] = acc[t][u][r];
            }
}

// Per-row loss: rank count + logsumexp over [cross_row, 0.8*intra_row(diag->0)].
// S: cross Gram (raw), Q: intra Gram (raw), inv_a: row-entity inv norms, inv_b: col-entity inv norms.
__global__ __launch_bounds__(256)
void row_loss(const float* __restrict__ S, const float* __restrict__ Q,
              const float* __restrict__ inv_a, const float* __restrict__ inv_b,
              float* __restrict__ out) {
    const int i = blockIdx.x;
    const int tid = threadIdx.x;
    const float invT = 1.0f / 0.03f;
    const float* Srow = S + (size_t)i * GN;
    const float* Qrow = Q + (size_t)i * GN;
    const float d_raw = Srow[i];
    const float ia = inv_a[i];

    float m = -1e30f;
    int cnt = 0;
    for (int j = tid; j < GN; j += 256) {
        float s = Srow[j];
        cnt += (s > d_raw) ? 1 : 0;
        float v1 = s * ia * inv_b[j] * invT;
        float q = Qrow[j];
        float v2 = (j == i) ? 0.0f : 0.8f * q * ia * inv_a[j] * invT;
        m = fmaxf(m, fmaxf(v1, v2));
    }
    #pragma unroll
    for (int off = 32; off > 0; off >>= 1) {
        m = fmaxf(m, __shfl_down(m, off));
        cnt += __shfl_down(cnt, off);
    }
    __shared__ float sm[4];
    __shared__ int sc[4];
    __shared__ float Msh;
    __shared__ int Csh;
    const int wave = tid >> 6, lane = tid & 63;
    if (lane == 0) { sm[wave] = m; sc[wave] = cnt; }
    __syncthreads();
    if (tid == 0) {
        Msh = fmaxf(fmaxf(sm[0], sm[1]), fmaxf(sm[2], sm[3]));
        Csh = sc[0] + sc[1] + sc[2] + sc[3];
    }
    __syncthreads();
    const float M = Msh;

    float sum = 0.f;
    for (int j = tid; j < GN; j += 256) {
        float s = Srow[j];
        float v1 = s * ia * inv_b[j] * invT;
        float q = Qrow[j];
        float v2 = (j == i) ? 0.0f : 0.8f * q * ia * inv_a[j] * invT;
        sum += __expf(v1 - M) + __expf(v2 - M);
    }
    #pragma unroll
    for (int off = 32; off > 0; off >>= 1) sum += __shfl_down(sum, off);
    if (lane == 0) sm[wave] = sum;
    __syncthreads();
    if (tid == 0) {
        float total = sm[0] + sm[1] + sm[2] + sm[3];
        int cc = Csh;
        float rank = 1.0f / (float)(GN - cc) + 1.0f;  // 1/(n - rank + 1) + 1
        float diag_logit = d_raw * ia * inv_b[i] * invT;
        float loss = rank * (M + logf(total) - diag_logit);
        atomicAdd(out, 0.5f * loss);
    }
}

extern "C" void kernel_launch(void* const* d_in, const int* in_sizes, int n_in,
                              void* d_out, int out_size, void* d_ws, size_t ws_size,
                              hipStream_t stream) {
    const float* brand = (const float*)d_in[0];
    const float* post  = (const float*)d_in[1];
    float* out = (float*)d_out;

    char* ws = (char*)d_ws;
    float* buf0 = (float*)ws;                                   // 64 MB: S then S^T
    float* buf1 = (float*)(ws + (size_t)GN * GN * 4);           // 64 MB: P then Br
    unsigned short* postb  = (unsigned short*)(ws + (size_t)GN * GN * 8);
    unsigned short* brandb = postb + (size_t)GN * GK;
    float* inv_post  = (float*)(brandb + (size_t)GN * GK);
    float* inv_brand = inv_post + GN;

    hipMemsetAsync(d_out, 0, sizeof(float) * out_size, stream);

    prep_kernel<<<GN, 256, 0, stream>>>(post,  postb,  inv_post);
    prep_kernel<<<GN, 256, 0, stream>>>(brand, brandb, inv_brand);

    dim3 grid(GN / BN, GN / BM);
    // S = post . brand^T ; P = post . post^T
    gemm_bt<<<grid, 256, 0, stream>>>(postb, brandb, buf0);
    gemm_bt<<<grid, 256, 0, stream>>>(postb, postb,  buf1);
    // loss_p: rows of S, intra = P, rank from row-ranks of S
    row_loss<<<GN, 256, 0, stream>>>(buf0, buf1, inv_post, inv_brand, out);
    // S^T = brand . post^T ; Br = brand . brand^T
    gemm_bt<<<grid, 256, 0, stream>>>(brandb, postb,  buf0);
    gemm_bt<<<grid, 256, 0, stream>>>(brandb, brandb, buf1);
    // loss_b: rows of S^T (= columns of S), intra = Br
    row_loss<<<GN, 256, 0, stream>>>(buf0, buf1, inv_brand, inv_post, out);
}

// Round 2
// 217.635 us; speedup vs baseline: 2.0736x; 2.0736x over previous
//
#include <hip/hip_runtime.h>

typedef __bf16 bf16_t;
typedef bf16_t bf16x8 __attribute__((ext_vector_type(8)));
typedef float floatx4 __attribute__((ext_vector_type(4)));

#define GN 4096
#define GK 1024
#define BM 128
#define BN 128
#define BK 32
#define LDK 40           // padded LDS row stride (bf16 elems)
#define INVT (1.0f/0.03f)
#define NTILES 528       // 32*33/2 upper-tri tiles

// fp32 -> bf16 RNE
static __device__ __forceinline__ unsigned short f2bf(float f) {
    unsigned u = __builtin_bit_cast(unsigned, f);
    u += 0x7fffu + ((u >> 16) & 1u);
    return (unsigned short)(u >> 16);
}
static __device__ __forceinline__ float bf2f(unsigned short b) {
    return __builtin_bit_cast(float, (unsigned)b << 16);
}

// Per-row: bf16 cast + inverse L2 norm
__global__ __launch_bounds__(256)
void prep_kernel(const float* __restrict__ X, unsigned short* __restrict__ Xb,
                 float* __restrict__ inv_norm) {
    const int i = blockIdx.x;
    const int tid = threadIdx.x;
    const float* row = X + (size_t)i * GK;
    unsigned short* rowb = Xb + (size_t)i * GK;
    float ss = 0.f;
    #pragma unroll
    for (int j = tid; j < GK; j += 256) {
        float f = row[j];
        ss += f * f;
        rowb[j] = f2bf(f);
    }
    #pragma unroll
    for (int off = 32; off > 0; off >>= 1) ss += __shfl_down(ss, off);
    __shared__ float sw[4];
    int wave = tid >> 6, lane = tid & 63;
    if (lane == 0) sw[wave] = ss;
    __syncthreads();
    if (tid == 0) inv_norm[i] = 1.0f / sqrtf(sw[0] + sw[1] + sw[2] + sw[3]);
}

// d[i] = dot(bf16(post_i), bf16(brand_i)) in fp32 — raw cross-Gram diagonal
__global__ __launch_bounds__(256)
void diag_kernel(const unsigned short* __restrict__ Pb, const unsigned short* __restrict__ Bb,
                 float* __restrict__ dvec) {
    const int i = blockIdx.x;
    const int tid = threadIdx.x;
    const unsigned short* pr = Pb + (size_t)i * GK;
    const unsigned short* br = Bb + (size_t)i * GK;
    float s = 0.f;
    #pragma unroll
    for (int j = tid; j < GK; j += 256) s += bf2f(pr[j]) * bf2f(br[j]);
    #pragma unroll
    for (int off = 32; off > 0; off >>= 1) s += __shfl_down(s, off);
    __shared__ float sw[4];
    int wave = tid >> 6, lane = tid & 63;
    if (lane == 0) sw[wave] = s;
    __syncthreads();
    if (tid == 0) dvec[i] = sw[0] + sw[1] + sw[2] + sw[3];
}

// ---- shared GEMM tile body (A[M,K] x B[N,K]^T, 128x128 tile) ----
// smem: 5120 floats (20480 B) = As(128*40 u16) ++ Bs(128*40 u16); reused as float red[] in epilogue.

#define GEMM_BODY(Aptr, Bptr)                                                          \
    unsigned short* As = (unsigned short*)smem;                                        \
    unsigned short* Bs = As + BM * LDK;                                                \
    const int lrow = lane & 15;                                                        \
    const int kq = lane >> 4;                                                          \
    floatx4 acc[4][4] = {};                                                            \
    for (int k0 = 0; k0 < GK; k0 += BK) {                                              \
        _Pragma("unroll")                                                              \
        for (int s = 0; s < 2; ++s) {                                                  \
            int q = tid + s * 256;                                                     \
            int r = q >> 2, c = q & 3;                                                 \
            const int4 av = *(const int4*)(Aptr + (size_t)(bm + r) * GK + k0 + c * 8); \
            const int4 bv = *(const int4*)(Bptr + (size_t)(bn + r) * GK + k0 + c * 8); \
            *(int4*)(As + r * LDK + c * 8) = av;                                       \
            *(int4*)(Bs + r * LDK + c * 8) = bv;                                       \
        }                                                                              \
        __syncthreads();                                                               \
        bf16x8 af[4], bfr[4];                                                          \
        _Pragma("unroll")                                                              \
        for (int t = 0; t < 4; ++t)                                                    \
            af[t] = *(const bf16x8*)(As + (wm + t * 16 + lrow) * LDK + kq * 8);        \
        _Pragma("unroll")                                                              \
        for (int u = 0; u < 4; ++u)                                                    \
            bfr[u] = *(const bf16x8*)(Bs + (wn + u * 16 + lrow) * LDK + kq * 8);       \
        _Pragma("unroll")                                                              \
        for (int t = 0; t < 4; ++t)                                                    \
            _Pragma("unroll")                                                          \
            for (int u = 0; u < 4; ++u)                                                \
                acc[t][u] = __builtin_amdgcn_mfma_f32_16x16x32_bf16(af[t], bfr[u],     \
                                                                    acc[t][u], 0, 0, 0); \
        __syncthreads();                                                               \
    }

// Cross GEMM S = post . brand^T with fused dual-sided softmax-partials + rank counts.
__global__ __launch_bounds__(256)
void cross_fused(const unsigned short* __restrict__ A, const unsigned short* __restrict__ B,
                 const float* __restrict__ dvec,
                 const float* __restrict__ inv_a, const float* __restrict__ inv_b,
                 float* __restrict__ sum_row, float* __restrict__ cnt_row,
                 float* __restrict__ sum_col, float* __restrict__ cnt_col) {
    __shared__ __align__(16) float smem[5120];
    __shared__ float s_ia[128], s_ib[128], s_da[128], s_db[128];

    const int tid = threadIdx.x;
    const int wave = tid >> 6, lane = tid & 63;
    const int bm = blockIdx.y * BM, bn = blockIdx.x * BN;
    const int wm = (wave >> 1) * 64, wn = (wave & 1) * 64;

    if (tid < 128) {
        s_ia[tid] = inv_a[bm + tid] * INVT;
        s_da[tid] = dvec[bm + tid];
    } else {
        int t2 = tid - 128;
        s_ib[t2] = inv_b[bn + t2];
        s_db[t2] = dvec[bn + t2];
    }
    // first __syncthreads inside GEMM_BODY covers this init

    GEMM_BODY(A, B)

    // ---- epilogue ----
    const int cn = lane & 15, rq = lane >> 4;
    float ia_r[4][4], da_r[4][4], ib_c[4], db_c[4];
    #pragma unroll
    for (int t = 0; t < 4; ++t)
        #pragma unroll
        for (int r = 0; r < 4; ++r) {
            int rl = wm + t * 16 + rq * 4 + r;
            ia_r[t][r] = s_ia[rl];
            da_r[t][r] = s_da[rl];
        }
    #pragma unroll
    for (int u = 0; u < 4; ++u) {
        int cl = wn + u * 16 + cn;
        ib_c[u] = s_ib[cl];
        db_c[u] = s_db[cl];
    }

    float rsum[4][4] = {}, rcnt[4][4] = {};
    float csum[4] = {}, ccnt[4] = {};
    #pragma unroll
    for (int t = 0; t < 4; ++t)
        #pragma unroll
        for (int u = 0; u < 4; ++u)
            #pragma unroll
            for (int r = 0; r < 4; ++r) {
                float s = acc[t][u][r];
                int grow = bm + wm + t * 16 + rq * 4 + r;
                int gcol = bn + wn + u * 16 + cn;
                float e = __expf(s * ia_r[t][r] * ib_c[u]);
                rsum[t][r] += e;
                csum[u] += e;
                bool offd = (grow != gcol);
                rcnt[t][r] += (offd && s > da_r[t][r]) ? 1.f : 0.f;
                ccnt[u]    += (offd && s > db_c[u])    ? 1.f : 0.f;
            }

    float* red = smem;
    const int rslot = cn + 16 * (wave & 1);   // 32 slots per row
    const int cslot = rq + 4 * (wave >> 1);   // 8 slots per col

    // Phase A: row exp-sums
    #pragma unroll
    for (int t = 0; t < 4; ++t)
        #pragma unroll
        for (int r = 0; r < 4; ++r)
            red[(wm + t * 16 + rq * 4 + r) * 33 + rslot] = rsum[t][r];
    __syncthreads();
    if (tid < 128) {
        float v = 0.f;
        #pragma unroll
        for (int s = 0; s < 32; ++s) v += red[tid * 33 + s];
        atomicAdd(&sum_row[bm + tid], v);
    }
    __syncthreads();
    // Phase B: row counts
    #pragma unroll
    for (int t = 0; t < 4; ++t)
        #pragma unroll
        for (int r = 0; r < 4; ++r)
            red[(wm + t * 16 + rq * 4 + r) * 33 + rslot] = rcnt[t][r];
    __syncthreads();
    if (tid < 128) {
        float v = 0.f;
        #pragma unroll
        for (int s = 0; s < 32; ++s) v += red[tid * 33 + s];
        atomicAdd(&cnt_row[bm + tid], v);
    }
    __syncthreads();
    // Phase C: col exp-sums
    #pragma unroll
    for (int u = 0; u < 4; ++u)
        red[(wn + u * 16 + cn) * 9 + cslot] = csum[u];
    __syncthreads();
    if (tid < 128) {
        float v = 0.f;
        #pragma unroll
        for (int s = 0; s < 8; ++s) v += red[tid * 9 + s];
        atomicAdd(&sum_col[bn + tid], v);
    }
    __syncthreads();
    // Phase D: col counts
    #pragma unroll
    for (int u = 0; u < 4; ++u)
        red[(wn + u * 16 + cn) * 9 + cslot] = ccnt[u];
    __syncthreads();
    if (tid < 128) {
        float v = 0.f;
        #pragma unroll
        for (int s = 0; s < 8; ++s) v += red[tid * 9 + s];
        atomicAdd(&cnt_col[bn + tid], v);
    }
}

// Intra Gram (symmetric): upper-tri tiles only; two problems (post, brand) in one grid.
__global__ __launch_bounds__(256)
void intra_fused(const unsigned short* __restrict__ X0, const unsigned short* __restrict__ X1,
                 const float* __restrict__ inv0, const float* __restrict__ inv1,
                 float* __restrict__ acc0, float* __restrict__ acc1) {
    __shared__ __align__(16) float smem[5120];
    __shared__ float s_ia[128], s_ib[128];

    int tt = blockIdx.x;
    const unsigned short* X;
    const float* invx;
    float* sacc;
    if (tt >= NTILES) { tt -= NTILES; X = X1; invx = inv1; sacc = acc1; }
    else              {               X = X0; invx = inv0; sacc = acc0; }

    // tt -> (I,J), I<=J, tt = J*(J+1)/2 + I
    int J = (int)((sqrtf(8.f * tt + 1.f) - 1.f) * 0.5f);
    while ((J + 1) * (J + 2) / 2 <= tt) ++J;
    while (J * (J + 1) / 2 > tt) --J;
    const int I = tt - J * (J + 1) / 2;
    const int bm = I * BM, bn = J * BN;
    const bool offdiag_tile = (I != J);

    const int tid = threadIdx.x;
    const int wave = tid >> 6, lane = tid & 63;
    const int wm = (wave >> 1) * 64, wn = (wave & 1) * 64;

    if (tid < 128) s_ia[tid] = invx[bm + tid] * (0.8f * INVT);
    else           s_ib[tid - 128] = invx[bn + (tid - 128)];

    GEMM_BODY(X, X)

    const int cn = lane & 15, rq = lane >> 4;
    float ia_r[4][4], ib_c[4];
    #pragma unroll
    for (int t = 0; t < 4; ++t)
        #pragma unroll
        for (int r = 0; r < 4; ++r)
            ia_r[t][r] = s_ia[wm + t * 16 + rq * 4 + r];
    #pragma unroll
    for (int u = 0; u < 4; ++u)
        ib_c[u] = s_ib[wn + u * 16 + cn];

    float rsum[4][4] = {}, csum[4] = {};
    #pragma unroll
    for (int t = 0; t < 4; ++t)
        #pragma unroll
        for (int u = 0; u < 4; ++u)
            #pragma unroll
            for (int r = 0; r < 4; ++r) {
                float s = acc[t][u][r];
                int grow = bm + wm + t * 16 + rq * 4 + r;
                int gcol = bn + wn + u * 16 + cn;
                float e = (grow == gcol) ? 1.0f : __expf(s * ia_r[t][r] * ib_c[u]);
                rsum[t][r] += e;
                csum[u] += e;
            }

    float* red = smem;
    const int rslot = cn + 16 * (wave & 1);
    const int cslot = rq + 4 * (wave >> 1);

    // rows always
    #pragma unroll
    for (int t = 0; t < 4; ++t)
        #pragma unroll
        for (int r = 0; r < 4; ++r)
            red[(wm + t * 16 + rq * 4 + r) * 33 + rslot] = rsum[t][r];
    __syncthreads();
    if (tid < 128) {
        float v = 0.f;
        #pragma unroll
        for (int s = 0; s < 32; ++s) v += red[tid * 33 + s];
        atomicAdd(&sacc[bm + tid], v);
    }
    // cols only for off-diagonal tiles (transpose contribution)
    if (offdiag_tile) {
        __syncthreads();
        #pragma unroll
        for (int u = 0; u < 4; ++u)
            red[(wn + u * 16 + cn) * 9 + cslot] = csum[u];
        __syncthreads();
        if (tid < 128) {
            float v = 0.f;
            #pragma unroll
            for (int s = 0; s < 8; ++s) v += red[tid * 9 + s];
            atomicAdd(&sacc[bn + tid], v);
        }
    }
}

// Final per-row loss assembly + global sum
__global__ __launch_bounds__(256)
void final_loss(const float* __restrict__ sum_post, const float* __restrict__ cnt_post,
                const float* __restrict__ sum_brand, const float* __restrict__ cnt_brand,
                const float* __restrict__ dvec,
                const float* __restrict__ inv_post, const float* __restrict__ inv_brand,
                float* __restrict__ out) {
    const int i = blockIdx.x * 256 + threadIdx.x;
    float dl = dvec[i] * inv_post[i] * inv_brand[i] * INVT;
    float lp = logf(sum_post[i]);
    float lb = logf(sum_brand[i]);
    float rp = 1.0f / (4096.0f - cnt_post[i]) + 1.0f;
    float rb = 1.0f / (4096.0f - cnt_brand[i]) + 1.0f;
    float loss = 0.5f * (rb * (lb - dl) + rp * (lp - dl));
    #pragma unroll
    for (int off = 32; off > 0; off >>= 1) loss += __shfl_down(loss, off);
    __shared__ float sw[4];
    int wave = threadIdx.x >> 6, lane = threadIdx.x & 63;
    if (lane == 0) sw[wave] = loss;
    __syncthreads();
    if (threadIdx.x == 0) atomicAdd(out, sw[0] + sw[1] + sw[2] + sw[3]);
}

extern "C" void kernel_launch(void* const* d_in, const int* in_sizes, int n_in,
                              void* d_out, int out_size, void* d_ws, size_t ws_size,
                              hipStream_t stream) {
    const float* brand = (const float*)d_in[0];
    const float* post  = (const float*)d_in[1];
    float* out = (float*)d_out;

    char* ws = (char*)d_ws;
    unsigned short* postb  = (unsigned short*)ws;                       // 8 MB
    unsigned short* brandb = postb + (size_t)GN * GK;                   // 8 MB
    float* inv_post  = (float*)(brandb + (size_t)GN * GK);
    float* inv_brand = inv_post + GN;
    float* dvec      = inv_brand + GN;
    float* accs      = dvec + GN;        // [sum_post, sum_brand, cnt_post, cnt_brand]
    float* sum_post  = accs;
    float* sum_brand = accs + GN;
    float* cnt_post  = accs + 2 * GN;
    float* cnt_brand = accs + 3 * GN;

    hipMemsetAsync(d_out, 0, sizeof(float) * out_size, stream);
    hipMemsetAsync(accs, 0, sizeof(float) * 4 * GN, stream);

    prep_kernel<<<GN, 256, 0, stream>>>(post,  postb,  inv_post);
    prep_kernel<<<GN, 256, 0, stream>>>(brand, brandb, inv_brand);
    diag_kernel<<<GN, 256, 0, stream>>>(postb, brandb, dvec);

    dim3 grid(GN / BN, GN / BM);
    cross_fused<<<grid, 256, 0, stream>>>(postb, brandb, dvec, inv_post, inv_brand,
                                          sum_post, cnt_post, sum_brand, cnt_brand);
    intra_fused<<<2 * NTILES, 256, 0, stream>>>(postb, brandb, inv_post, inv_brand,
                                                sum_post, sum_brand);
    final_loss<<<GN / 256, 256, 0, stream>>>(sum_post, cnt_post, sum_brand, cnt_brand,
                                             dvec, inv_post, inv_brand, out);
}

// Round 3
// 197.202 us; speedup vs baseline: 2.2884x; 1.1036x over previous
//
#include <hip/hip_runtime.h>

typedef __bf16 bf16_t;
typedef bf16_t bf16x8 __attribute__((ext_vector_type(8)));
typedef float floatx4 __attribute__((ext_vector_type(4)));

#define GN 4096
#define GK 1024
#define BM 128
#define BN 128
#define BK 32           // unpadded LDS row stride (u16 elems) — required by global_load_lds
#define INVT (1.0f/0.03f)
#define NTILES 528      // 32*33/2 upper-tri tiles

// fp32 -> bf16 RNE
static __device__ __forceinline__ unsigned short f2bf(float f) {
    unsigned u = __builtin_bit_cast(unsigned, f);
    u += 0x7fffu + ((u >> 16) & 1u);
    return (unsigned short)(u >> 16);
}
static __device__ __forceinline__ float bf2f(unsigned short b) {
    return __builtin_bit_cast(float, (unsigned)b << 16);
}

// Per-row: bf16 cast + inverse L2 norm
__global__ __launch_bounds__(256)
void prep_kernel(const float* __restrict__ X, unsigned short* __restrict__ Xb,
                 float* __restrict__ inv_norm) {
    const int i = blockIdx.x;
    const int tid = threadIdx.x;
    const float* row = X + (size_t)i * GK;
    unsigned short* rowb = Xb + (size_t)i * GK;
    float ss = 0.f;
    #pragma unroll
    for (int j = tid; j < GK; j += 256) {
        float f = row[j];
        ss += f * f;
        rowb[j] = f2bf(f);
    }
    #pragma unroll
    for (int off = 32; off > 0; off >>= 1) ss += __shfl_down(ss, off);
    __shared__ float sw[4];
    int wave = tid >> 6, lane = tid & 63;
    if (lane == 0) sw[wave] = ss;
    __syncthreads();
    if (tid == 0) inv_norm[i] = 1.0f / sqrtf(sw[0] + sw[1] + sw[2] + sw[3]);
}

// d[i] = dot(bf16(post_i), bf16(brand_i)) in fp32 — raw cross-Gram diagonal
__global__ __launch_bounds__(256)
void diag_kernel(const unsigned short* __restrict__ Pb, const unsigned short* __restrict__ Bb,
                 float* __restrict__ dvec) {
    const int i = blockIdx.x;
    const int tid = threadIdx.x;
    const unsigned short* pr = Pb + (size_t)i * GK;
    const unsigned short* br = Bb + (size_t)i * GK;
    float s = 0.f;
    #pragma unroll
    for (int j = tid; j < GK; j += 256) s += bf2f(pr[j]) * bf2f(br[j]);
    #pragma unroll
    for (int off = 32; off > 0; off >>= 1) s += __shfl_down(s, off);
    __shared__ float sw[4];
    int wave = tid >> 6, lane = tid & 63;
    if (lane == 0) sw[wave] = s;
    __syncthreads();
    if (tid == 0) dvec[i] = sw[0] + sw[1] + sw[2] + sw[3];
}

// ---- shared GEMM tile body (A[M,K] x B[N,K]^T, 128x128 tile) ----
// LDS tiles are UNPADDED (BK=32 u16 = 64 B rows): global_load_lds writes
// wave-uniform base + lane*16B, so layout must be contiguous in lane order.
// Each wave per K-step: 2 A-DMAs + 2 B-DMAs, each covering 16 rows (1 KiB).

#define GEMM_BODY(Aptr, Bptr)                                                           \
    unsigned short* As = (unsigned short*)smem;                                         \
    unsigned short* Bs = As + BM * BK;                                                  \
    const int lrow = lane & 15;                                                         \
    const int kq = lane >> 4;                                                           \
    const int srow = lane >> 2;          /* row within 16-row DMA strip */              \
    const int scol = (lane & 3) * 8;     /* u16 k-chunk within row */                   \
    floatx4 acc[4][4] = {};                                                             \
    for (int k0 = 0; k0 < GK; k0 += BK) {                                               \
        _Pragma("unroll")                                                               \
        for (int s = 0; s < 2; ++s) {                                                   \
            const int r0 = (wave * 2 + s) * 16;                                         \
            const int gr = r0 + srow;                                                   \
            __builtin_amdgcn_global_load_lds(                                           \
                (const __attribute__((address_space(1))) void*)                         \
                    (Aptr + (size_t)(bm + gr) * GK + k0 + scol),                        \
                (__attribute__((address_space(3))) void*)(As + r0 * BK), 16, 0, 0);     \
            __builtin_amdgcn_global_load_lds(                                           \
                (const __attribute__((address_space(1))) void*)                         \
                    (Bptr + (size_t)(bn + gr) * GK + k0 + scol),                        \
                (__attribute__((address_space(3))) void*)(Bs + r0 * BK), 16, 0, 0);     \
        }                                                                               \
        __syncthreads();                                                                \
        bf16x8 af[4], bfr[4];                                                           \
        _Pragma("unroll")                                                               \
        for (int t = 0; t < 4; ++t)                                                     \
            af[t] = *(const bf16x8*)(As + (wm + t * 16 + lrow) * BK + kq * 8);          \
        _Pragma("unroll")                                                               \
        for (int u = 0; u < 4; ++u)                                                     \
            bfr[u] = *(const bf16x8*)(Bs + (wn + u * 16 + lrow) * BK + kq * 8);         \
        _Pragma("unroll")                                                               \
        for (int t = 0; t < 4; ++t)                                                     \
            _Pragma("unroll")                                                           \
            for (int u = 0; u < 4; ++u)                                                 \
                acc[t][u] = __builtin_amdgcn_mfma_f32_16x16x32_bf16(af[t], bfr[u],      \
                                                                    acc[t][u], 0, 0, 0);\
        __syncthreads();                                                                \
    }

// Cross GEMM S = post . brand^T with fused dual-sided softmax-partials + rank counts.
__global__ __launch_bounds__(256)
void cross_fused(const unsigned short* __restrict__ A, const unsigned short* __restrict__ B,
                 const float* __restrict__ dvec,
                 const float* __restrict__ inv_a, const float* __restrict__ inv_b,
                 float* __restrict__ sum_row, float* __restrict__ cnt_row,
                 float* __restrict__ sum_col, float* __restrict__ cnt_col) {
    // union: GEMM tiles (2*8 KiB) / epilogue redA+redB (2*128*33 floats = 33 KiB)
    __shared__ __align__(16) float smem[8448];
    __shared__ float s_ia[128], s_ib[128], s_da[128], s_db[128];

    const int tid = threadIdx.x;
    const int wave = tid >> 6, lane = tid & 63;
    const int bm = blockIdx.y * BM, bn = blockIdx.x * BN;
    const int wm = (wave >> 1) * 64, wn = (wave & 1) * 64;

    if (tid < 128) {
        s_ia[tid] = inv_a[bm + tid] * INVT;
        s_da[tid] = dvec[bm + tid];
    } else {
        int t2 = tid - 128;
        s_ib[t2] = inv_b[bn + t2];
        s_db[t2] = dvec[bn + t2];
    }
    // first __syncthreads inside GEMM_BODY covers this init

    GEMM_BODY(A, B)

    // ---- epilogue ----
    const int cn = lane & 15, rq = lane >> 4;
    float ia_r[4][4], da_r[4][4], ib_c[4], db_c[4];
    #pragma unroll
    for (int t = 0; t < 4; ++t)
        #pragma unroll
        for (int r = 0; r < 4; ++r) {
            int rl = wm + t * 16 + rq * 4 + r;
            ia_r[t][r] = s_ia[rl];
            da_r[t][r] = s_da[rl];
        }
    #pragma unroll
    for (int u = 0; u < 4; ++u) {
        int cl = wn + u * 16 + cn;
        ib_c[u] = s_ib[cl];
        db_c[u] = s_db[cl];
    }

    float rsum[4][4] = {}, rcnt[4][4] = {};
    float csum[4] = {}, ccnt[4] = {};
    #pragma unroll
    for (int t = 0; t < 4; ++t)
        #pragma unroll
        for (int u = 0; u < 4; ++u)
            #pragma unroll
            for (int r = 0; r < 4; ++r) {
                float s = acc[t][u][r];
                int grow = bm + wm + t * 16 + rq * 4 + r;
                int gcol = bn + wn + u * 16 + cn;
                float e = __expf(s * ia_r[t][r] * ib_c[u]);
                rsum[t][r] += e;
                csum[u] += e;
                bool offd = (grow != gcol);
                rcnt[t][r] += (offd && s > da_r[t][r]) ? 1.f : 0.f;
                ccnt[u]    += (offd && s > db_c[u])    ? 1.f : 0.f;
            }

    float* redA = smem;
    float* redB = smem + 4224;
    const int rslot = cn + 16 * (wave & 1);   // 32 slots per row
    const int cslot = rq + 4 * (wave >> 1);   // 8 slots per col

    // Phase 1: row exp-sums + row counts (one barrier)
    #pragma unroll
    for (int t = 0; t < 4; ++t)
        #pragma unroll
        for (int r = 0; r < 4; ++r) {
            int idx = (wm + t * 16 + rq * 4 + r) * 33 + rslot;
            redA[idx] = rsum[t][r];
            redB[idx] = rcnt[t][r];
        }
    __syncthreads();
    if (tid < 128) {
        float v = 0.f, w = 0.f;
        #pragma unroll
        for (int s = 0; s < 32; ++s) { v += redA[tid * 33 + s]; w += redB[tid * 33 + s]; }
        atomicAdd(&sum_row[bm + tid], v);
        atomicAdd(&cnt_row[bm + tid], w);
    }
    __syncthreads();
    // Phase 2: col exp-sums + col counts
    #pragma unroll
    for (int u = 0; u < 4; ++u) {
        int idx = (wn + u * 16 + cn) * 9 + cslot;
        redA[idx] = csum[u];
        redB[idx] = ccnt[u];
    }
    __syncthreads();
    if (tid < 128) {
        float v = 0.f, w = 0.f;
        #pragma unroll
        for (int s = 0; s < 8; ++s) { v += redA[tid * 9 + s]; w += redB[tid * 9 + s]; }
        atomicAdd(&sum_col[bn + tid], v);
        atomicAdd(&cnt_col[bn + tid], w);
    }
}

// Intra Gram (symmetric): upper-tri tiles only; two problems (post, brand) in one grid.
__global__ __launch_bounds__(256)
void intra_fused(const unsigned short* __restrict__ X0, const unsigned short* __restrict__ X1,
                 const float* __restrict__ inv0, const float* __restrict__ inv1,
                 float* __restrict__ acc0, float* __restrict__ acc1) {
    // union: GEMM tiles (16 KiB) / epilogue red (128*33 floats = 16.9 KiB)
    __shared__ __align__(16) float smem[4224];
    __shared__ float s_ia[128], s_ib[128];

    int tt = blockIdx.x;
    const unsigned short* X;
    const float* invx;
    float* sacc;
    if (tt >= NTILES) { tt -= NTILES; X = X1; invx = inv1; sacc = acc1; }
    else              {               X = X0; invx = inv0; sacc = acc0; }

    // tt -> (I,J), I<=J, tt = J*(J+1)/2 + I
    int J = (int)((sqrtf(8.f * tt + 1.f) - 1.f) * 0.5f);
    while ((J + 1) * (J + 2) / 2 <= tt) ++J;
    while (J * (J + 1) / 2 > tt) --J;
    const int I = tt - J * (J + 1) / 2;
    const int bm = I * BM, bn = J * BN;
    const bool offdiag_tile = (I != J);

    const int tid = threadIdx.x;
    const int wave = tid >> 6, lane = tid & 63;
    const int wm = (wave >> 1) * 64, wn = (wave & 1) * 64;

    if (tid < 128) s_ia[tid] = invx[bm + tid] * (0.8f * INVT);
    else           s_ib[tid - 128] = invx[bn + (tid - 128)];

    GEMM_BODY(X, X)

    const int cn = lane & 15, rq = lane >> 4;
    float ia_r[4][4], ib_c[4];
    #pragma unroll
    for (int t = 0; t < 4; ++t)
        #pragma unroll
        for (int r = 0; r < 4; ++r)
            ia_r[t][r] = s_ia[wm + t * 16 + rq * 4 + r];
    #pragma unroll
    for (int u = 0; u < 4; ++u)
        ib_c[u] = s_ib[wn + u * 16 + cn];

    float rsum[4][4] = {}, csum[4] = {};
    #pragma unroll
    for (int t = 0; t < 4; ++t)
        #pragma unroll
        for (int u = 0; u < 4; ++u)
            #pragma unroll
            for (int r = 0; r < 4; ++r) {
                float s = acc[t][u][r];
                int grow = bm + wm + t * 16 + rq * 4 + r;
                int gcol = bn + wn + u * 16 + cn;
                float e = (grow == gcol) ? 1.0f : __expf(s * ia_r[t][r] * ib_c[u]);
                rsum[t][r] += e;
                csum[u] += e;
            }

    float* red = smem;
    const int rslot = cn + 16 * (wave & 1);
    const int cslot = rq + 4 * (wave >> 1);

    // rows always
    #pragma unroll
    for (int t = 0; t < 4; ++t)
        #pragma unroll
        for (int r = 0; r < 4; ++r)
            red[(wm + t * 16 + rq * 4 + r) * 33 + rslot] = rsum[t][r];
    __syncthreads();
    if (tid < 128) {
        float v = 0.f;
        #pragma unroll
        for (int s = 0; s < 32; ++s) v += red[tid * 33 + s];
        atomicAdd(&sacc[bm + tid], v);
    }
    // cols only for off-diagonal tiles (transpose contribution)
    if (offdiag_tile) {
        __syncthreads();
        #pragma unroll
        for (int u = 0; u < 4; ++u)
            red[(wn + u * 16 + cn) * 9 + cslot] = csum[u];
        __syncthreads();
        if (tid < 128) {
            float v = 0.f;
            #pragma unroll
            for (int s = 0; s < 8; ++s) v += red[tid * 9 + s];
            atomicAdd(&sacc[bn + tid], v);
        }
    }
}

// Final per-row loss assembly + global sum
__global__ __launch_bounds__(256)
void final_loss(const float* __restrict__ sum_post, const float* __restrict__ cnt_post,
                const float* __restrict__ sum_brand, const float* __restrict__ cnt_brand,
                const float* __restrict__ dvec,
                const float* __restrict__ inv_post, const float* __restrict__ inv_brand,
                float* __restrict__ out) {
    const int i = blockIdx.x * 256 + threadIdx.x;
    float dl = dvec[i] * inv_post[i] * inv_brand[i] * INVT;
    float lp = logf(sum_post[i]);
    float lb = logf(sum_brand[i]);
    float rp = 1.0f / (4096.0f - cnt_post[i]) + 1.0f;
    float rb = 1.0f / (4096.0f - cnt_brand[i]) + 1.0f;
    float loss = 0.5f * (rb * (lb - dl) + rp * (lp - dl));
    #pragma unroll
    for (int off = 32; off > 0; off >>= 1) loss += __shfl_down(loss, off);
    __shared__ float sw[4];
    int wave = threadIdx.x >> 6, lane = threadIdx.x & 63;
    if (lane == 0) sw[wave] = loss;
    __syncthreads();
    if (threadIdx.x == 0) atomicAdd(out, sw[0] + sw[1] + sw[2] + sw[3]);
}

extern "C" void kernel_launch(void* const* d_in, const int* in_sizes, int n_in,
                              void* d_out, int out_size, void* d_ws, size_t ws_size,
                              hipStream_t stream) {
    const float* brand = (const float*)d_in[0];
    const float* post  = (const float*)d_in[1];
    float* out = (float*)d_out;

    char* ws = (char*)d_ws;
    unsigned short* postb  = (unsigned short*)ws;                       // 8 MB
    unsigned short* brandb = postb + (size_t)GN * GK;                   // 8 MB
    float* inv_post  = (float*)(brandb + (size_t)GN * GK);
    float* inv_brand = inv_post + GN;
    float* dvec      = inv_brand + GN;
    float* accs      = dvec + GN;        // [sum_post, sum_brand, cnt_post, cnt_brand]
    float* sum_post  = accs;
    float* sum_brand = accs + GN;
    float* cnt_post  = accs + 2 * GN;
    float* cnt_brand = accs + 3 * GN;

    hipMemsetAsync(d_out, 0, sizeof(float) * out_size, stream);
    hipMemsetAsync(accs, 0, sizeof(float) * 4 * GN, stream);

    prep_kernel<<<GN, 256, 0, stream>>>(post,  postb,  inv_post);
    prep_kernel<<<GN, 256, 0, stream>>>(brand, brandb, inv_brand);
    diag_kernel<<<GN, 256, 0, stream>>>(postb, brandb, dvec);

    dim3 grid(GN / BN, GN / BM);
    cross_fused<<<grid, 256, 0, stream>>>(postb, brandb, dvec, inv_post, inv_brand,
                                          sum_post, cnt_post, sum_brand, cnt_brand);
    intra_fused<<<2 * NTILES, 256, 0, stream>>>(postb, brandb, inv_post, inv_brand,
                                                sum_post, sum_brand);
    final_loss<<<GN / 256, 256, 0, stream>>>(sum_post, cnt_post, sum_brand, cnt_brand,
                                             dvec, inv_post, inv_brand, out);
}